// Round 1
// baseline (109.419 us; speedup 1.0000x reference)
//
#include <hip/hip_runtime.h>
#include <math.h>

// Problem constants
#define TT 64
#define NN 32
#define CC 128
#define DD 64

// ---------------------------------------------------------------------------
// Kernel 1: one wave (64 lanes) per (n,c) unit. lane = jeffress dim d.
// Runs the T=64 scan of the per-(n,c) dynamics, emits fs[t] for each t.
// fsbuf layout: [(n*C + c)][t]  (t contiguous, coalesced store per wave)
// ---------------------------------------------------------------------------
__global__ __launch_bounds__(256) void k1_percell(
    const float* __restrict__ x,    // (T,N,2,C)
    const float* __restrict__ w1,   // (10,1)
    const float* __restrict__ b1,   // (10,)
    const float* __restrict__ w2,   // (1,10)
    const float* __restrict__ b2,   // (1,)
    float* __restrict__ fsbuf)      // (N*C, T)
{
#pragma clang fp contract(off)
    const int lane = threadIdx.x & 63;
    const int wid  = (blockIdx.x << 2) + (threadIdx.x >> 6);  // global wave id = n*C + c
    const int n = wid >> 7;         // / C
    const int c = wid & 127;        // % C

    // preload the two delay-line inputs: lane t holds x0[t], x1[t]
    const float x0 = x[((lane * NN + n) * 2 + 0) * CC + c];
    const float x1 = x[((lane * NN + n) * 2 + 1) * CC + c];

    // jeffress integrator kernel weight for d = lane
    int dist = lane - (DD / 2);
    int ad = dist < 0 ? -dist : dist;
    if (ad == 0) ad = 1;                       // center clamped to NN weight
    const float kint = 1.0f / (1.0f - expf(-(float)ad * 0.5f));

    // weights (broadcast loads)
    float W1[10], B1[10], W2[10];
#pragma unroll
    for (int k = 0; k < 10; ++k) { W1[k] = w1[k]; B1[k] = b1[k]; W2[k] = w2[k]; }
    const float B2 = b2[0];

    // state
    float vj = 0.f, vi = 0.f, f1 = 0.f, v2 = 0.f, fs = 0.f, fskeep = 0.f;
    float v1[10], f2[10];
#pragma unroll
    for (int k = 0; k < 10; ++k) { v1[k] = 0.f; f2[k] = 0.f; }

    for (int t = 0; t < TT; ++t) {
        // u[t, d=lane] = x0[t-lane] + x1[t-63+lane]  (0 outside range)
        const int ia = t - lane;
        const int ib = t - (DD - 1) + lane;
        const float a = __shfl(x0, ia & 63);
        const float b = __shfl(x1, ib & 63);
        const float u = (ia >= 0 ? a : 0.0f) + (ib >= 0 ? b : 0.0f);

        // jeffress LIF (tau=20, decay_input, hard reset)
        vj = vj + (u - vj) / 20.0f;
        const float sj = vj >= 1.0f ? 1.0f : 0.0f;
        vj *= (1.0f - sj);

        // integrator linear (D->1) + IF
        float zc = sj * kint;
#pragma unroll
        for (int off = 32; off; off >>= 1) zc += __shfl_xor(zc, off);
        vi += zc;
        const float si = vi >= 1.0f ? 1.0f : 0.0f;
        vi *= (1.0f - si);

        // square model: filter -> Linear(1,10) -> IF -> filter -> Linear(10,1) -> IF
        f1 = f1 * 0.5f + si;
        float acc = 0.f;
#pragma unroll
        for (int k = 0; k < 10; ++k) {
            v1[k] += f1 * W1[k] + B1[k];
            const float s1 = v1[k] >= 1.0f ? 1.0f : 0.0f;
            v1[k] *= (1.0f - s1);
            f2[k] = f2[k] * 0.5f + s1;
            acc += f2[k] * W2[k];
        }
        v2 += acc + B2;
        const float s2 = v2 >= 1.0f ? 1.0f : 0.0f;
        v2 *= (1.0f - s2);

        // sum filter (per (n,c)); keep value at t == lane
        fs = fs * 0.5f + s2;
        if (t == lane) fskeep = fs;
    }

    fsbuf[wid * TT + lane] = fskeep;   // coalesced: lane = t
}

// ---------------------------------------------------------------------------
// Kernel 2: one block (64 threads = 1 wave) per n.
// Loads fs[n, :, :] (C x T) into LDS transposed [t][c] (pad 129), then the
// sequential T scan: vs IF + sqrt model (32-dim, lane-parallel).
// ---------------------------------------------------------------------------
__global__ __launch_bounds__(64) void k2_pern(
    const float* __restrict__ fsbuf, // (N*C, T)
    const float* __restrict__ sw0,   // (32,1)
    const float* __restrict__ sb0,   // (32,)
    const float* __restrict__ sw1,   // (32,32)
    const float* __restrict__ sb1,   // (32,)
    const float* __restrict__ sw2,   // (1,32)
    const float* __restrict__ sb2,   // (1,)
    float* __restrict__ out)         // (T,N,1)
{
#pragma clang fp contract(off)
    __shared__ float lds[TT * 129];
    const int n = blockIdx.x;
    const int lane = threadIdx.x;      // 0..63

    // load + transpose: fsbuf[n*8192 + c*64 + t] -> lds[t*129 + c]
    const float* src = fsbuf + n * (CC * TT);
    for (int i = lane; i < CC * TT; i += 64) {
        const int cc = i >> 6;
        const int tt = i & 63;
        lds[tt * 129 + cc] = src[i];
    }
    __syncthreads();

    // sqrt-model weights. lane = k + 32*h (h = hi half of the 32x32 matvec)
    const int k = lane & 31;
    const int h = lane >> 5;
    const float SW0 = sw0[k];
    const float SB0 = sb0[k];
    const float SB1 = sb1[k];
    float SW1[16];
#pragma unroll
    for (int j = 0; j < 16; ++j) SW1[j] = sw1[k * 32 + h * 16 + j];
    const float SW2j = sw2[lane & 31];   // used only when lane < 32
    const float SB2 = sb2[0];

    float vs = 0.f, g0 = 0.f, q0 = 0.f, g1 = 0.f, q1 = 0.f, g2 = 0.f, q2 = 0.f;

    for (int t = 0; t < TT; ++t) {
        // sum over C of fs[t,n,c]
        float p = lds[t * 129 + lane] + lds[t * 129 + 64 + lane];
#pragma unroll
        for (int off = 32; off; off >>= 1) p += __shfl_xor(p, off);

        vs += p;
        const float s = vs >= 1.0f ? 1.0f : 0.0f;
        vs *= (1.0f - s);
        const float hsp = s;

        // sqrt model (mirrored on lanes 32..63; consistent by construction)
        g0 = g0 * 0.5f + hsp;
        q0 += hsp * SW0 + SB0;
        const float s0 = q0 >= 1.0f ? 1.0f : 0.0f;
        q0 *= (1.0f - s0);
        g1 = g1 * 0.5f + s0;

        // q1[k] += sum_j sw1[k,j]*g1[j] ; split across the two half-waves
        float a0 = 0.f, a1 = 0.f, a2 = 0.f, a3 = 0.f;
#pragma unroll
        for (int j = 0; j < 16; j += 4) {
            a0 += SW1[j + 0] * __shfl(g1, h * 16 + j + 0);
            a1 += SW1[j + 1] * __shfl(g1, h * 16 + j + 1);
            a2 += SW1[j + 2] * __shfl(g1, h * 16 + j + 2);
            a3 += SW1[j + 3] * __shfl(g1, h * 16 + j + 3);
        }
        float part = (a0 + a1) + (a2 + a3);
        part += __shfl_xor(part, 32);      // combine the two halves
        q1 += part + SB1;
        const float s1 = q1 >= 1.0f ? 1.0f : 0.0f;
        q1 *= (1.0f - s1);
        g2 = g2 * 0.5f + s1;

        // q2 += sum_j g2[j]*sw2[j]  (NonSpikingIF, no reset)
        float pv = (lane < 32) ? g2 * SW2j : 0.0f;
#pragma unroll
        for (int off = 32; off; off >>= 1) pv += __shfl_xor(pv, off);
        q2 += pv + SB2;

        if (lane == 0) out[t * NN + n] = q2;
    }
}

// ---------------------------------------------------------------------------
extern "C" void kernel_launch(void* const* d_in, const int* in_sizes, int n_in,
                              void* d_out, int out_size, void* d_ws, size_t ws_size,
                              hipStream_t stream)
{
    const float* x   = (const float*)d_in[0];
    const float* w1  = (const float*)d_in[1];
    const float* b1  = (const float*)d_in[2];
    const float* w2  = (const float*)d_in[3];
    const float* b2  = (const float*)d_in[4];
    const float* sw0 = (const float*)d_in[5];
    const float* sb0 = (const float*)d_in[6];
    const float* sw1 = (const float*)d_in[7];
    const float* sb1 = (const float*)d_in[8];
    const float* sw2 = (const float*)d_in[9];
    const float* sb2 = (const float*)d_in[10];
    float* out = (float*)d_out;

    float* fsbuf = (float*)d_ws;   // N*C*T floats = 1 MiB

    // Kernel 1: N*C = 4096 waves, 4 waves/block -> 1024 blocks
    hipLaunchKernelGGL(k1_percell, dim3((NN * CC) / 4), dim3(256), 0, stream,
                       x, w1, b1, w2, b2, fsbuf);

    // Kernel 2: one wave per n
    hipLaunchKernelGGL(k2_pern, dim3(NN), dim3(64), 0, stream,
                       fsbuf, sw0, sb0, sw1, sb1, sw2, sb2, out);
}

// Round 2
// 58.364 us; speedup vs baseline: 1.8748x; 1.8748x over previous
//
#include <hip/hip_runtime.h>
#include <math.h>

// Problem constants
#define TT 64
#define NN 32
#define CC 128
#define DD 64

// ---------------------------------------------------------------------------
// DPP helpers: linear wave reduce-to-lane63 (VALU pipe, no DS traffic)
// ---------------------------------------------------------------------------
#define DPPADD(x, ctrl, rm)                                                   \
    x += __builtin_bit_cast(float, __builtin_amdgcn_update_dpp(               \
             0, __builtin_bit_cast(int, x), ctrl, rm, 0xf, false))

__device__ __forceinline__ float wave_reduce63(float x) {
    DPPADD(x, 0x111, 0xf);  // row_shr:1
    DPPADD(x, 0x112, 0xf);  // row_shr:2
    DPPADD(x, 0x114, 0xf);  // row_shr:4
    DPPADD(x, 0x118, 0xf);  // row_shr:8  -> lane15/31/47/63 hold row sums
    DPPADD(x, 0x142, 0xa);  // row_bcast:15 (rows 1,3) -> lane31, lane63
    DPPADD(x, 0x143, 0xc);  // row_bcast:31 (rows 2,3) -> lane63 = total
    return x;
}

__device__ __forceinline__ float rdlane(float x, int l) {
    return __builtin_bit_cast(float,
        __builtin_amdgcn_readlane(__builtin_bit_cast(int, x), l));
}

// ---------------------------------------------------------------------------
// Kernel 1a: one wave per (n,c). lane = jeffress dim d.
// Delay lines realized as pre-shifted ballot bitmasks (no shuffles).
// Emits the integrator-IF spike train as a 64-bit mask per cell.
// ---------------------------------------------------------------------------
__global__ __launch_bounds__(256) void k1a_jeffress(
    const float* __restrict__ x,                 // (T,N,2,C)
    unsigned long long* __restrict__ simask)     // (N*C)
{
#pragma clang fp contract(off)
    const int lane = threadIdx.x & 63;
    const int wid  = (blockIdx.x << 2) + (threadIdx.x >> 6);  // n*C + c
    const int n = wid >> 7;
    const int c = wid & 127;

    // lane t holds x0[t], x1[t]; ballot -> uniform bitmasks over time
    const float x0 = x[((lane * NN + n) * 2 + 0) * CC + c];
    const float x1 = x[((lane * NN + n) * 2 + 1) * CC + c];
    // pre-shift: at step t, LSB of msh0 = x0[t-lane], LSB of msh1 = x1[t-63+lane]
    unsigned long long msh0 = __ballot(x0 > 0.5f) << lane;
    unsigned long long msh1 = __ballot(x1 > 0.5f) << (63 - lane);

    int ad = lane - (DD / 2);
    if (ad < 0) ad = -ad;
    if (ad == 0) ad = 1;                         // center clamp
    const float kint = 1.0f / (1.0f - expf(-(float)ad * 0.5f));

    float vj = 0.f, vi = 0.f, sreg = 0.f;
    for (int t = 0; t < TT; ++t) {
        const float u = (float)((int)(msh0 & 1ull) + (int)(msh1 & 1ull));
        msh0 >>= 1; msh1 >>= 1;

        // jeffress LIF (tau=20, decay_input, hard reset)
        vj = vj + (u - vj) / 20.0f;
        const float sj = vj >= 1.0f ? 1.0f : 0.0f;
        vj *= (1.0f - sj);

        // integrator linear D->1 (DPP reduce) + IF
        float zc = wave_reduce63(sj * kint);
        vi += rdlane(zc, 63);
        const float si = vi >= 1.0f ? 1.0f : 0.0f;
        vi *= (1.0f - si);

        if (t == lane) sreg = si;                // lane t captures step t's spike
    }
    unsigned long long m = __ballot(sreg > 0.5f);
    if (lane == 0) simask[wid] = m;
}

// ---------------------------------------------------------------------------
// Kernel B: one block per n, 128 threads.
// Phase 1: lane-per-cell square-model chains -> fs[t][c] in LDS.
// Phase 2: wave 0, lane t sums fs[t][:] over C.
// Phase 3: wave 0 runs the per-n scan (vs IF + sqrt model, 32-dim).
// ---------------------------------------------------------------------------
__global__ __launch_bounds__(128) void kB_pern(
    const unsigned long long* __restrict__ simask, // (N*C)
    const float* __restrict__ w1,  const float* __restrict__ b1,
    const float* __restrict__ w2,  const float* __restrict__ b2,
    const float* __restrict__ sw0, const float* __restrict__ sb0,
    const float* __restrict__ sw1, const float* __restrict__ sb1,
    const float* __restrict__ sw2, const float* __restrict__ sb2,
    float* __restrict__ out)                       // (T,N,1)
{
#pragma clang fp contract(off)
    __shared__ float fsl[TT][CC + 1];
    const int n = blockIdx.x;
    const int tid = threadIdx.x;                   // 0..127 = cell c

    // ---- phase 1: square model per cell ----
    {
        unsigned long long sm = simask[n * CC + tid];
        float W1[10], B1[10], W2[10];
#pragma unroll
        for (int k = 0; k < 10; ++k) { W1[k] = w1[k]; B1[k] = b1[k]; W2[k] = w2[k]; }
        const float B2 = b2[0];
        float f1 = 0.f, v2 = 0.f, fs = 0.f;
        float v1[10], f2[10];
#pragma unroll
        for (int k = 0; k < 10; ++k) { v1[k] = 0.f; f2[k] = 0.f; }

        for (int t = 0; t < TT; ++t) {
            const float si = (float)((int)(sm & 1ull)); sm >>= 1;
            f1 = f1 * 0.5f + si;
            float acc = 0.f;
#pragma unroll
            for (int k = 0; k < 10; ++k) {
                v1[k] += f1 * W1[k] + B1[k];
                const float s1 = v1[k] >= 1.0f ? 1.0f : 0.0f;
                v1[k] *= (1.0f - s1);
                f2[k] = f2[k] * 0.5f + s1;
                acc += f2[k] * W2[k];
            }
            v2 += acc + B2;
            const float s2 = v2 >= 1.0f ? 1.0f : 0.0f;
            v2 *= (1.0f - s2);
            fs = fs * 0.5f + s2;
            fsl[t][tid] = fs;
        }
    }
    __syncthreads();
    if (tid >= 64) return;                         // wave 1 done

    // ---- phase 2: lane tt sums row tt over the 128 cells ----
    float sums;
    {
        float a0 = 0.f, a1 = 0.f, a2 = 0.f, a3 = 0.f;
        const float* row = &fsl[tid][0];
#pragma unroll
        for (int c = 0; c < CC; c += 4) {
            a0 += row[c + 0]; a1 += row[c + 1];
            a2 += row[c + 2]; a3 += row[c + 3];
        }
        sums = (a0 + a1) + (a2 + a3);
    }

    // ---- phase 3: per-n scan on wave 0. lane = k + 32*h ----
    const int k = tid & 31;
    const int h = tid >> 5;
    const float SW0 = sw0[k], SB0 = sb0[k], SB1 = sb1[k];
    float SW1[16];
#pragma unroll
    for (int j = 0; j < 16; ++j) SW1[j] = sw1[k * 32 + h * 16 + j];
    const float SW2j = (tid < 32) ? sw2[k] : 0.0f;
    const float SB2 = sb2[0];

    float vs = 0.f, g0 = 0.f, q0 = 0.f, g1 = 0.f, q1 = 0.f, g2 = 0.f, q2 = 0.f;

    for (int t = 0; t < TT; ++t) {
        const float p = rdlane(sums, t);

        vs += p;
        const float s = vs >= 1.0f ? 1.0f : 0.0f;
        vs *= (1.0f - s);

        g0 = g0 * 0.5f + s;
        q0 += s * SW0 + SB0;
        const float s0 = q0 >= 1.0f ? 1.0f : 0.0f;
        q0 *= (1.0f - s0);
        g1 = g1 * 0.5f + s0;

        // q1[k] += sum_j sw1[k,j]*g1[j], split across the two half-waves
        float a0 = 0.f, a1 = 0.f, a2 = 0.f, a3 = 0.f;
#pragma unroll
        for (int j = 0; j < 16; j += 4) {
            a0 += SW1[j + 0] * __shfl(g1, h * 16 + j + 0);
            a1 += SW1[j + 1] * __shfl(g1, h * 16 + j + 1);
            a2 += SW1[j + 2] * __shfl(g1, h * 16 + j + 2);
            a3 += SW1[j + 3] * __shfl(g1, h * 16 + j + 3);
        }
        float part = (a0 + a1) + (a2 + a3);
        part += __shfl_xor(part, 32);
        q1 += part + SB1;
        const float s1 = q1 >= 1.0f ? 1.0f : 0.0f;
        q1 *= (1.0f - s1);
        g2 = g2 * 0.5f + s1;

        // q2 += sum_j g2[j]*sw2[j]  (NonSpikingIF, no reset)
        float pv = g2 * SW2j;
        pv = wave_reduce63(pv);
        q2 += rdlane(pv, 63) + SB2;

        if (tid == 0) out[t * NN + n] = q2;
    }
}

// ---------------------------------------------------------------------------
extern "C" void kernel_launch(void* const* d_in, const int* in_sizes, int n_in,
                              void* d_out, int out_size, void* d_ws, size_t ws_size,
                              hipStream_t stream)
{
    const float* x   = (const float*)d_in[0];
    const float* w1  = (const float*)d_in[1];
    const float* b1  = (const float*)d_in[2];
    const float* w2  = (const float*)d_in[3];
    const float* b2  = (const float*)d_in[4];
    const float* sw0 = (const float*)d_in[5];
    const float* sb0 = (const float*)d_in[6];
    const float* sw1 = (const float*)d_in[7];
    const float* sb1 = (const float*)d_in[8];
    const float* sw2 = (const float*)d_in[9];
    const float* sb2 = (const float*)d_in[10];
    float* out = (float*)d_out;

    unsigned long long* simask = (unsigned long long*)d_ws;  // 4096 * 8B = 32 KiB

    hipLaunchKernelGGL(k1a_jeffress, dim3((NN * CC) / 4), dim3(256), 0, stream,
                       x, simask);
    hipLaunchKernelGGL(kB_pern, dim3(NN), dim3(128), 0, stream,
                       simask, w1, b1, w2, b2, sw0, sb0, sw1, sb1, sw2, sb2, out);
}